// Round 8
// baseline (187.250 us; speedup 1.0000x reference)
//
#include <hip/hip_runtime.h>
#include <hip/hip_bf16.h>

typedef unsigned short u16;
typedef __attribute__((ext_vector_type(8))) short short8;   // 8 bf16 = 4 VGPRs (MFMA A/B frag)
typedef __attribute__((ext_vector_type(4))) float floatx4;  // MFMA C/D frag

#define SEQ    1024
#define EMB    768
#define NHEADS 12
#define HDIM   64
#define QKVD   2304   // 3*EMB
#define BATCH  8
#define ROWS   8192   // BATCH*SEQ
#define QKW    1536   // width of the Q|K buffer (V split out)

__device__ __forceinline__ u16 f2bf(float f) {           // RNE
  unsigned int x; __builtin_memcpy(&x, &f, 4);
  x = (x + 0x7FFFu + ((x >> 16) & 1u)) >> 16;
  return (u16)x;
}
// pack two floats' bf16-truncations into one u32 (low = a, high = b)
__device__ __forceinline__ unsigned int pack2bf_t(float a, float b) {
  unsigned int ua, ub;
  __builtin_memcpy(&ua, &a, 4); __builtin_memcpy(&ub, &b, 4);
  return (ub & 0xFFFF0000u) | (ua >> 16);
}

// async global->LDS, 16B per lane. LDS dest must be wave-chunk base + lane*16 (m104);
// the GLOBAL address is per-lane-free, which lets us XOR-permute the source.
__device__ __forceinline__ void gld16(const void* g, void* l) {
  __builtin_amdgcn_global_load_lds(
      (const __attribute__((address_space(1))) void*)g,
      (__attribute__((address_space(3))) void*)l, 16, 0, 0);
}

// raw barrier control: wait only the OLDER tiles' loads (never vmcnt(0) mid-pipeline).
#define PIPE_BARRIER_VM(N) asm volatile("s_waitcnt vmcnt(" #N ")\n\ts_barrier" ::: "memory")
#define PIPE_BARRIER       asm volatile("s_barrier" ::: "memory")

// ---------------- prep: x fp32->bf16 + both weight transposes, one launch ----------------
// blocks [0,3072): convert x (8 elems/thread). [3072,3072+2304): 32x32 transpose tiles,
// of which x-tiles [0,72) = w_qkv, [72,96) = w_out.
__global__ __launch_bounds__(256) void prep(const float* __restrict__ x,
                                            const float* __restrict__ wqkv,
                                            const float* __restrict__ wout,
                                            u16* __restrict__ xb,
                                            u16* __restrict__ dqkv,
                                            u16* __restrict__ dout) {
  const int t = threadIdx.x;
  if (blockIdx.x < 3072) {
    const int i = (blockIdx.x * 256 + t) * 8;
    u16 tmp[8];
#pragma unroll
    for (int j = 0; j < 8; ++j) tmp[j] = f2bf(x[i + j]);
    *(uint4*)(xb + i) = *(const uint4*)tmp;
    return;
  }
  __shared__ u16 tile[32][33];
  const int bid = blockIdx.x - 3072;          // [0,2304)
  const int bx = bid % 96, by = bid / 96;     // (96,24) grid
  const bool second = bx >= 72;
  const float* in = second ? wout : wqkv;
  u16* out = second ? dout : dqkv;
  const int C = second ? EMB : QKVD;
  const int c0 = (second ? bx - 72 : bx) * 32, r0 = by * 32;
  const int tx = t & 31, ty = t >> 5;         // 32 x 8
#pragma unroll
  for (int i = 0; i < 4; ++i)
    tile[ty + i * 8][tx] = f2bf(in[(size_t)(r0 + ty + i * 8) * C + c0 + tx]);
  __syncthreads();
#pragma unroll
  for (int i = 0; i < 4; ++i)
    out[(size_t)(c0 + ty + i * 8) * EMB + r0 + tx] = tile[tx][ty + i * 8];
}

// ---------------- QKV GEMM: [8192,768] x [2304,768]^T -> qk + vT ----------------
// BK=64, double-buffered async pipeline (raw vmcnt barriers), XOR LDS swizzle,
// XCD-aware block swizzle (groups of 144 = 8 m-stripes).
__global__ __launch_bounds__(256) void gemm_qkv(const u16* __restrict__ A,
                                                const u16* __restrict__ Bt,
                                                u16* __restrict__ qk,
                                                u16* __restrict__ vT) {
  constexpr int K = EMB, ITERS = K / 64;
  __shared__ __align__(16) u16 As[2][128 * 64];
  __shared__ __align__(16) u16 Bs[2][128 * 64];
  const int t = threadIdx.x;
  const int w = t >> 6, lane = t & 63, l16 = lane & 15, quad = lane >> 4;
  const int wm = (w >> 1) * 64, wn = (w & 1) * 64;
  const int flat = blockIdx.y * 18 + blockIdx.x;
  const int grp = flat / 144, loc = flat % 144;
  const int m0 = (grp * 8 + (loc & 7)) * 128;
  const int n0 = (loc >> 3) * 128;

  auto stage = [&](int k0, int buf) {   // 8 gld16 per thread
#pragma unroll
    for (int i = 0; i < 4; ++i) {
      const int idx = i * 256 + t;
      const int row = idx >> 3;
      const int gc8 = (((idx & 7) ^ (row & 7)) << 3);
      gld16(A  + (size_t)(m0 + row) * K + k0 + gc8, &As[buf][(size_t)idx * 8]);
      gld16(Bt + (size_t)(n0 + row) * K + k0 + gc8, &Bs[buf][(size_t)idx * 8]);
    }
  };

  floatx4 acc[4][4];
#pragma unroll
  for (int mt = 0; mt < 4; ++mt)
#pragma unroll
    for (int nt = 0; nt < 4; ++nt) acc[mt][nt] = (floatx4){0.f, 0.f, 0.f, 0.f};

  stage(0, 0);
  for (int it = 0; it < ITERS; ++it) {
    const int cur = it & 1;
    if (it + 1 < ITERS) {
      stage((it + 1) * 64, cur ^ 1);
      PIPE_BARRIER_VM(8);
    } else {
      PIPE_BARRIER_VM(0);
    }
#pragma unroll
    for (int kk = 0; kk < 2; ++kk) {
      short8 a[4], b[4];
#pragma unroll
      for (int mt = 0; mt < 4; ++mt) {
        const int row = wm + mt * 16 + l16;
        a[mt] = *(const short8*)(&As[cur][row * 64 + ((((kk << 2) + quad) ^ (row & 7)) << 3)]);
      }
#pragma unroll
      for (int nt = 0; nt < 4; ++nt) {
        const int row = wn + nt * 16 + l16;
        b[nt] = *(const short8*)(&Bs[cur][row * 64 + ((((kk << 2) + quad) ^ (row & 7)) << 3)]);
      }
#pragma unroll
      for (int mt = 0; mt < 4; ++mt)
#pragma unroll
        for (int nt = 0; nt < 4; ++nt)
          acc[mt][nt] = __builtin_amdgcn_mfma_f32_16x16x32_bf16(a[mt], b[nt], acc[mt][nt], 0, 0, 0);
    }
    PIPE_BARRIER;
  }

  if (n0 < QKW) {
#pragma unroll
    for (int mt = 0; mt < 4; ++mt)
#pragma unroll
      for (int nt = 0; nt < 4; ++nt) {
        const int col = n0 + wn + nt * 16 + l16;
#pragma unroll
        for (int r = 0; r < 4; ++r) {
          const int row = m0 + wm + mt * 16 + quad * 4 + r;
          qk[(size_t)row * QKW + col] = f2bf(acc[mt][nt][r]);
        }
      }
  } else {
#pragma unroll
    for (int mt = 0; mt < 4; ++mt) {
      const int rowb = m0 + wm + mt * 16 + quad * 4;
      const int b = rowb >> 10, n = rowb & 1023;
#pragma unroll
      for (int nt = 0; nt < 4; ++nt) {
        const int vc = n0 + wn + nt * 16 + l16 - QKW;
        const int h = vc >> 6, d = vc & 63;
        ushort4 pk;
        pk.x = f2bf(acc[mt][nt][0]); pk.y = f2bf(acc[mt][nt][1]);
        pk.z = f2bf(acc[mt][nt][2]); pk.w = f2bf(acc[mt][nt][3]);
        *(ushort4*)(vT + ((size_t)(b * NHEADS + h) * HDIM + d) * SEQ + n) = pk;
      }
    }
  }
}

// ---------------- flash attention ----------------
// grid (B*H, SEQ/128); 4 waves x 32 queries. 32-key tiles, 3-deep prefetch.
// S^T = mfma(K,Q); P via LDS round-trip; l = P*ones via MFMA (consistent with PV,
// lands in O's D-row layout -> no shuffles). All LDS XOR-swizzled, zero padding.
__global__ __launch_bounds__(256) void flash_attn(const u16* __restrict__ qk,
                                                  const u16* __restrict__ vT,
                                                  u16* __restrict__ aout) {
  __shared__ __align__(16) u16 QPs[128 * 64];     // Q tile; per-wave P tiles alias it
  __shared__ __align__(16) u16 Ks[3][32 * 64];    // K rows [key][d]
  __shared__ __align__(16) u16 Vs[3][64 * 32];    // V^T rows [d][key]

  const int t = threadIdx.x;
  const int w = t >> 6, lane = t & 63, l16 = lane & 15, quad = lane >> 4;
  const int bh = blockIdx.x, b = bh / NHEADS, h = bh % NHEADS;
  const int m0 = blockIdx.y * 128;
  constexpr float C_EXP = 0.125f * 1.44269504f;   // fold 1/sqrt(64) into exp2
  constexpr int ITERS = SEQ / 32;

  const size_t kbase = (size_t)(b * SEQ) * QKW + EMB + h * HDIM;
  const size_t vbase = (size_t)bh * HDIM * SEQ;

  auto stage = [&](int n0, int buf) {   // 2 gld16 per thread
    const int kr = t >> 3, ck = t & 7;            // K: 32 rows x 64
    gld16(qk + kbase + (size_t)(n0 + kr) * QKW + ((ck ^ (kr & 7)) << 3),
          &Ks[buf][(size_t)t * 8]);
    const int dr = t >> 2, cv = t & 3;            // V^T: 64 rows x 32
    gld16(vT + vbase + (size_t)dr * SEQ + n0 + ((cv ^ (dr & 3)) << 3),
          &Vs[buf][(size_t)t * 8]);
  };

  stage(0, 0);
  stage(32, 1);

  // stage Q 128x64, XOR-swizzled
  const size_t qbase = (size_t)(b * SEQ + m0) * QKW + h * HDIM;
#pragma unroll
  for (int i = 0; i < 4; ++i) {
    const int idx = i * 256 + t, row = idx >> 3, c = idx & 7;
    *(uint4*)(QPs + row * 64 + ((c ^ (row & 7)) << 3)) =
        *(const uint4*)(qk + qbase + (size_t)row * QKW + (c << 3));
  }
  __syncthreads();  // prologue: drains Q stores AND tiles 0,1

  // hoist Q as B-operand frags: B[j=query][k=d], j=l16
  short8 bq[2][2];
#pragma unroll
  for (int mt = 0; mt < 2; ++mt)
#pragma unroll
    for (int kc = 0; kc < 2; ++kc)
      bq[mt][kc] = *(const short8*)(QPs + (w * 32 + mt * 16 + l16) * 64 +
                                    ((((kc << 2) + quad) ^ (l16 & 7)) << 3));

  short8 ones;
#pragma unroll
  for (int j = 0; j < 8; ++j) ones[j] = (short)0x3F80;  // bf16 1.0

  floatx4 o[2][4], lcc[2];
#pragma unroll
  for (int mt = 0; mt < 2; ++mt) {
    lcc[mt] = (floatx4){0.f, 0.f, 0.f, 0.f};
#pragma unroll
    for (int ct = 0; ct < 4; ++ct) o[mt][ct] = (floatx4){0.f, 0.f, 0.f, 0.f};
  }

  u16* Pw = QPs + w * 32 * 64;  // per-wave P region (aliases this wave's dead Q rows)

  int cur = 0;
  for (int it = 0; it < ITERS; ++it) {
    int nxt = cur + 2; if (nxt >= 3) nxt -= 3;
    if (it + 2 < ITERS) {
      stage((it + 2) * 32, nxt);
      PIPE_BARRIER_VM(4);      // drain tile it; it+1, it+2 stay in flight
    } else if (it + 1 < ITERS) {
      PIPE_BARRIER_VM(2);
    } else {
      PIPE_BARRIER_VM(0);
    }

    // S^T: st[kt][mt], D[key = kt*16+quad*4+r][query = mt*16+l16]
    floatx4 st[2][2];
#pragma unroll
    for (int kt = 0; kt < 2; ++kt)
#pragma unroll
      for (int mt = 0; mt < 2; ++mt) st[kt][mt] = (floatx4){0.f, 0.f, 0.f, 0.f};
#pragma unroll
    for (int kt = 0; kt < 2; ++kt) {
      const int krow = (kt * 16 + l16) * 64;
      const short8 ak0 = *(const short8*)(&Ks[cur][krow + (((0 + quad) ^ (l16 & 7)) << 3)]);
      const short8 ak1 = *(const short8*)(&Ks[cur][krow + (((4 + quad) ^ (l16 & 7)) << 3)]);
#pragma unroll
      for (int mt = 0; mt < 2; ++mt) {
        st[kt][mt] = __builtin_amdgcn_mfma_f32_16x16x32_bf16(ak0, bq[mt][0], st[kt][mt], 0, 0, 0);
        st[kt][mt] = __builtin_amdgcn_mfma_f32_16x16x32_bf16(ak1, bq[mt][1], st[kt][mt], 0, 0, 0);
      }
    }

    // exp + packed b64 P-store: P[m=query][n=key], swizzled chunk16
#pragma unroll
    for (int mt = 0; mt < 2; ++mt)
#pragma unroll
      for (int kt = 0; kt < 2; ++kt) {
        const float p0 = __builtin_amdgcn_exp2f(st[kt][mt][0] * C_EXP);
        const float p1 = __builtin_amdgcn_exp2f(st[kt][mt][1] * C_EXP);
        const float p2 = __builtin_amdgcn_exp2f(st[kt][mt][2] * C_EXP);
        const float p3 = __builtin_amdgcn_exp2f(st[kt][mt][3] * C_EXP);
        uint2 pw2;
        pw2.x = pack2bf_t(p0, p1);
        pw2.y = pack2bf_t(p2, p3);
        *(uint2*)(Pw + (mt * 16 + l16) * 64 +
                  ((((kt << 1) + (quad >> 1)) ^ (l16 & 7)) << 3) + ((quad & 1) << 2)) = pw2;
      }

    // O += P V ; l += P * 1  (same A-frag -> numerator/denominator consistent)
#pragma unroll
    for (int mt = 0; mt < 2; ++mt) {
      const short8 ap = *(const short8*)(Pw + (mt * 16 + l16) * 64 +
                                        ((quad ^ (l16 & 7)) << 3));
      lcc[mt] = __builtin_amdgcn_mfma_f32_16x16x32_bf16(ap, ones, lcc[mt], 0, 0, 0);
#pragma unroll
      for (int ct = 0; ct < 4; ++ct) {
        const short8 bv = *(const short8*)(&Vs[cur][(ct * 16 + l16) * 32 +
                                                    ((quad ^ (l16 & 3)) << 3)]);
        o[mt][ct] = __builtin_amdgcn_mfma_f32_16x16x32_bf16(ap, bv, o[mt][ct], 0, 0, 0);
      }
    }
    PIPE_BARRIER;
    cur = (cur + 1 == 3) ? 0 : cur + 1;
  }

  // epilogue: l lives in the same D-rows as O (row = quad*4+r) -> in-lane normalize
#pragma unroll
  for (int mt = 0; mt < 2; ++mt) {
    floatx4 inv;
#pragma unroll
    for (int r = 0; r < 4; ++r) inv[r] = 1.f / lcc[mt][r];
#pragma unroll
    for (int ct = 0; ct < 4; ++ct)
#pragma unroll
      for (int r = 0; r < 4; ++r) {
        const int row = m0 + w * 32 + mt * 16 + quad * 4 + r;
        const int col = h * HDIM + ct * 16 + l16;
        aout[(size_t)(b * SEQ + row) * EMB + col] = f2bf(o[mt][ct][r] * inv[r]);
      }
  }
}

// ---------------- out GEMM: [8192,768] x [768,768]^T + bias -> fp32 ----------------
// 64x128 tile, BK=64 double-buffered pipeline, XOR swizzle, XCD groups of 48.
__global__ __launch_bounds__(256) void gemm_out(const u16* __restrict__ A,
                                                const u16* __restrict__ Bt,
                                                const float* __restrict__ bias,
                                                float* __restrict__ C) {
  constexpr int K = EMB, N = EMB, ITERS = K / 64;
  __shared__ __align__(16) u16 As[2][64 * 64];
  __shared__ __align__(16) u16 Bs[2][128 * 64];
  const int t = threadIdx.x;
  const int w = t >> 6, lane = t & 63, l16 = lane & 15, quad = lane >> 4;
  const int wm = (w >> 1) * 32, wn = (w & 1) * 64;
  const int flat = blockIdx.y * 6 + blockIdx.x;
  const int grp = flat / 48, loc = flat % 48;
  const int m0 = (grp * 8 + (loc & 7)) * 64;
  const int n0 = (loc >> 3) * 128;

  auto stage = [&](int k0, int buf) {   // 6 gld16 per thread
#pragma unroll
    for (int i = 0; i < 2; ++i) {
      const int idx = i * 256 + t;
      const int row = idx >> 3;
      const int gc8 = (((idx & 7) ^ (row & 7)) << 3);
      gld16(A + (size_t)(m0 + row) * K + k0 + gc8, &As[buf][(size_t)idx * 8]);
    }
#pragma unroll
    for (int i = 0; i < 4; ++i) {
      const int idx = i * 256 + t;
      const int row = idx >> 3;
      const int gc8 = (((idx & 7) ^ (row & 7)) << 3);
      gld16(Bt + (size_t)(n0 + row) * K + k0 + gc8, &Bs[buf][(size_t)idx * 8]);
    }
  };

  floatx4 acc[2][4];
#pragma unroll
  for (int mt = 0; mt < 2; ++mt)
#pragma unroll
    for (int nt = 0; nt < 4; ++nt) acc[mt][nt] = (floatx4){0.f, 0.f, 0.f, 0.f};

  stage(0, 0);
  for (int it = 0; it < ITERS; ++it) {
    const int cur = it & 1;
    if (it + 1 < ITERS) {
      stage((it + 1) * 64, cur ^ 1);
      PIPE_BARRIER_VM(6);
    } else {
      PIPE_BARRIER_VM(0);
    }
#pragma unroll
    for (int kk = 0; kk < 2; ++kk) {
      short8 a[2], b[4];
#pragma unroll
      for (int mt = 0; mt < 2; ++mt) {
        const int row = wm + mt * 16 + l16;
        a[mt] = *(const short8*)(&As[cur][row * 64 + ((((kk << 2) + quad) ^ (row & 7)) << 3)]);
      }
#pragma unroll
      for (int nt = 0; nt < 4; ++nt) {
        const int row = wn + nt * 16 + l16;
        b[nt] = *(const short8*)(&Bs[cur][row * 64 + ((((kk << 2) + quad) ^ (row & 7)) << 3)]);
      }
#pragma unroll
      for (int mt = 0; mt < 2; ++mt)
#pragma unroll
        for (int nt = 0; nt < 4; ++nt)
          acc[mt][nt] = __builtin_amdgcn_mfma_f32_16x16x32_bf16(a[mt], b[nt], acc[mt][nt], 0, 0, 0);
    }
    PIPE_BARRIER;
  }

#pragma unroll
  for (int mt = 0; mt < 2; ++mt)
#pragma unroll
    for (int nt = 0; nt < 4; ++nt) {
      const int col = n0 + wn + nt * 16 + l16;
      const float badd = bias[col];
#pragma unroll
      for (int r = 0; r < 4; ++r) {
        const int row = m0 + wm + mt * 16 + quad * 4 + r;
        C[(size_t)row * N + col] = acc[mt][nt][r] + badd;
      }
    }
}

// ---------------- launch ----------------
extern "C" void kernel_launch(void* const* d_in, const int* in_sizes, int n_in,
                              void* d_out, int out_size, void* d_ws, size_t ws_size,
                              hipStream_t stream) {
  const float* x     = (const float*)d_in[0];  // [8192, 768]
  const float* w_qkv = (const float*)d_in[1];  // [768, 2304]
  const float* w_out = (const float*)d_in[2];  // [768, 768]
  const float* b_out = (const float*)d_in[3];  // [768]
  float* out = (float*)d_out;                  // [8192, 768] fp32

  // ws (u16 units); xb dead after QKV GEMM -> aliased with aout.
  u16* qk    = (u16*)d_ws;                      // 8192*1536
  u16* vT    = qk    + (size_t)ROWS * QKW;      // 96*64*1024
  u16* xb    = vT    + (size_t)BATCH * NHEADS * HDIM * SEQ;  // 8192*768
  u16* aout  = xb;
  u16* wqkvT = xb    + (size_t)ROWS * EMB;      // 2304*768
  u16* woutT = wqkvT + (size_t)QKVD * EMB;      // 768*768

  prep<<<3072 + 2304, 256, 0, stream>>>(x, w_qkv, w_out, xb, wqkvT, woutT);

  gemm_qkv<<<dim3(18, 64), 256, 0, stream>>>(xb, wqkvT, qk, vT);

  flash_attn<<<dim3(BATCH * NHEADS, SEQ / 128), 256, 0, stream>>>(qk, vT, aout);

  gemm_out<<<dim3(6, 128), 256, 0, stream>>>(aout, woutT, b_out, out);
}

// Round 9
// 183.690 us; speedup vs baseline: 1.0194x; 1.0194x over previous
//
#include <hip/hip_runtime.h>
#include <hip/hip_bf16.h>

typedef unsigned short u16;
typedef __attribute__((ext_vector_type(8))) short short8;   // 8 bf16 = 4 VGPRs (MFMA A/B frag)
typedef __attribute__((ext_vector_type(4))) float floatx4;  // MFMA C/D frag

#define SEQ    1024
#define EMB    768
#define NHEADS 12
#define HDIM   64
#define QKVD   2304   // 3*EMB
#define BATCH  8
#define ROWS   8192   // BATCH*SEQ
#define QKW    1536   // width of the Q|K buffer (V split out)

__device__ __forceinline__ u16 f2bf(float f) {           // RNE
  unsigned int x; __builtin_memcpy(&x, &f, 4);
  x = (x + 0x7FFFu + ((x >> 16) & 1u)) >> 16;
  return (u16)x;
}
// pack two floats' bf16-truncations into one u32 (low = a, high = b)
__device__ __forceinline__ unsigned int pack2bf_t(float a, float b) {
  unsigned int ua, ub;
  __builtin_memcpy(&ua, &a, 4); __builtin_memcpy(&ub, &b, 4);
  return (ub & 0xFFFF0000u) | (ua >> 16);
}

// async global->LDS, 16B per lane. LDS dest must be wave-chunk base + lane*16 (m104);
// the GLOBAL address is per-lane-free, which lets us XOR-permute the source.
__device__ __forceinline__ void gld16(const void* g, void* l) {
  __builtin_amdgcn_global_load_lds(
      (const __attribute__((address_space(1))) void*)g,
      (__attribute__((address_space(3))) void*)l, 16, 0, 0);
}

// raw barrier control: wait only the OLDER tiles' loads (never vmcnt(0) mid-pipeline).
#define PIPE_BARRIER_VM(N) asm volatile("s_waitcnt vmcnt(" #N ")\n\ts_barrier" ::: "memory")
#define PIPE_BARRIER       asm volatile("s_barrier" ::: "memory")

// ---------------- prep: x fp32->bf16 + both weight transposes, one launch ----------------
__global__ __launch_bounds__(256) void prep(const float* __restrict__ x,
                                            const float* __restrict__ wqkv,
                                            const float* __restrict__ wout,
                                            u16* __restrict__ xb,
                                            u16* __restrict__ dqkv,
                                            u16* __restrict__ dout) {
  const int t = threadIdx.x;
  if (blockIdx.x < 3072) {
    const int i = (blockIdx.x * 256 + t) * 8;
    u16 tmp[8];
#pragma unroll
    for (int j = 0; j < 8; ++j) tmp[j] = f2bf(x[i + j]);
    *(uint4*)(xb + i) = *(const uint4*)tmp;
    return;
  }
  __shared__ u16 tile[32][33];
  const int bid = blockIdx.x - 3072;          // [0,2304)
  const int bx = bid % 96, by = bid / 96;
  const bool second = bx >= 72;
  const float* in = second ? wout : wqkv;
  u16* out = second ? dout : dqkv;
  const int C = second ? EMB : QKVD;
  const int c0 = (second ? bx - 72 : bx) * 32, r0 = by * 32;
  const int tx = t & 31, ty = t >> 5;
#pragma unroll
  for (int i = 0; i < 4; ++i)
    tile[ty + i * 8][tx] = f2bf(in[(size_t)(r0 + ty + i * 8) * C + c0 + tx]);
  __syncthreads();
#pragma unroll
  for (int i = 0; i < 4; ++i)
    out[(size_t)(c0 + ty + i * 8) * EMB + r0 + tx] = tile[tx][ty + i * 8];
}

// ---------------- QKV GEMM: [8192,768] x [2304,768]^T -> qk + vT ----------------
// Q columns pre-scaled by 0.125*log2(e) so flash's exp2 needs no multiply.
__global__ __launch_bounds__(256) void gemm_qkv(const u16* __restrict__ A,
                                                const u16* __restrict__ Bt,
                                                u16* __restrict__ qk,
                                                u16* __restrict__ vT) {
  constexpr int K = EMB, ITERS = K / 64;
  __shared__ __align__(16) u16 As[2][128 * 64];
  __shared__ __align__(16) u16 Bs[2][128 * 64];
  const int t = threadIdx.x;
  const int w = t >> 6, lane = t & 63, l16 = lane & 15, quad = lane >> 4;
  const int wm = (w >> 1) * 64, wn = (w & 1) * 64;
  const int flat = blockIdx.y * 18 + blockIdx.x;
  const int grp = flat / 144, loc = flat % 144;
  const int m0 = (grp * 8 + (loc & 7)) * 128;
  const int n0 = (loc >> 3) * 128;

  auto stage = [&](int k0, int buf) {   // 8 gld16 per thread
#pragma unroll
    for (int i = 0; i < 4; ++i) {
      const int idx = i * 256 + t;
      const int row = idx >> 3;
      const int gc8 = (((idx & 7) ^ (row & 7)) << 3);
      gld16(A  + (size_t)(m0 + row) * K + k0 + gc8, &As[buf][(size_t)idx * 8]);
      gld16(Bt + (size_t)(n0 + row) * K + k0 + gc8, &Bs[buf][(size_t)idx * 8]);
    }
  };

  floatx4 acc[4][4];
#pragma unroll
  for (int mt = 0; mt < 4; ++mt)
#pragma unroll
    for (int nt = 0; nt < 4; ++nt) acc[mt][nt] = (floatx4){0.f, 0.f, 0.f, 0.f};

  stage(0, 0);
  for (int it = 0; it < ITERS; ++it) {
    const int cur = it & 1;
    if (it + 1 < ITERS) {
      stage((it + 1) * 64, cur ^ 1);
      PIPE_BARRIER_VM(8);
    } else {
      PIPE_BARRIER_VM(0);
    }
#pragma unroll
    for (int kk = 0; kk < 2; ++kk) {
      short8 a[4], b[4];
#pragma unroll
      for (int mt = 0; mt < 4; ++mt) {
        const int row = wm + mt * 16 + l16;
        a[mt] = *(const short8*)(&As[cur][row * 64 + ((((kk << 2) + quad) ^ (row & 7)) << 3)]);
      }
#pragma unroll
      for (int nt = 0; nt < 4; ++nt) {
        const int row = wn + nt * 16 + l16;
        b[nt] = *(const short8*)(&Bs[cur][row * 64 + ((((kk << 2) + quad) ^ (row & 7)) << 3)]);
      }
#pragma unroll
      for (int mt = 0; mt < 4; ++mt)
#pragma unroll
        for (int nt = 0; nt < 4; ++nt)
          acc[mt][nt] = __builtin_amdgcn_mfma_f32_16x16x32_bf16(a[mt], b[nt], acc[mt][nt], 0, 0, 0);
    }
    PIPE_BARRIER;
  }

  if (n0 < QKW) {
    const float qs = (n0 < EMB) ? 0.1803368801111f : 1.0f;  // 0.125*log2(e) on Q cols
#pragma unroll
    for (int mt = 0; mt < 4; ++mt)
#pragma unroll
      for (int nt = 0; nt < 4; ++nt) {
        const int col = n0 + wn + nt * 16 + l16;
#pragma unroll
        for (int r = 0; r < 4; ++r) {
          const int row = m0 + wm + mt * 16 + quad * 4 + r;
          qk[(size_t)row * QKW + col] = f2bf(acc[mt][nt][r] * qs);
        }
      }
  } else {
#pragma unroll
    for (int mt = 0; mt < 4; ++mt) {
      const int rowb = m0 + wm + mt * 16 + quad * 4;
      const int b = rowb >> 10, n = rowb & 1023;
#pragma unroll
      for (int nt = 0; nt < 4; ++nt) {
        const int vc = n0 + wn + nt * 16 + l16 - QKW;
        const int h = vc >> 6, d = vc & 63;
        ushort4 pk;
        pk.x = f2bf(acc[mt][nt][0]); pk.y = f2bf(acc[mt][nt][1]);
        pk.z = f2bf(acc[mt][nt][2]); pk.w = f2bf(acc[mt][nt][3]);
        *(ushort4*)(vT + ((size_t)(b * NHEADS + h) * HDIM + d) * SEQ + n) = pk;
      }
    }
  }
}

// ---------------- flash attention (register-resident P) ----------------
// grid (B*H, SEQ/128); 4 waves x 32 queries. S^T = mfma(K,Q) -> exp2 in regs ->
// P^T used DIRECTLY as Y-operand of O^T = mfma(V-perm, P^T): no P LDS round-trip.
// V X-operand read with key permutation pi(8q+j) = {4q+j, 16+4q+j-4} (2x ds_read_b64,
// 2-way banks = free). l = mfma(ones, P^T) -> indexed by query=l16, in-lane with O^T.
// K/V triple-buffered gld16 (48 KB, 3 blocks/CU), vmcnt(8) steady-state. Q frags
// load straight from global (no Q LDS, no prologue __syncthreads).
__global__ __launch_bounds__(256) void flash_attn(const u16* __restrict__ qk,
                                                  const u16* __restrict__ vT,
                                                  u16* __restrict__ aout) {
  __shared__ __align__(16) u16 Ks[3][64 * 64];   // [key][d]
  __shared__ __align__(16) u16 Vs[3][64 * 64];   // [d][key]

  const int t = threadIdx.x;
  const int w = t >> 6, lane = t & 63, l16 = lane & 15, quad = lane >> 4;
  const int bh = blockIdx.x, b = bh / NHEADS, h = bh % NHEADS;
  const int m0 = blockIdx.y * 128;
  constexpr int ITERS = SEQ / 64;
  const int swz = l16 & 7;

  const size_t kbase = (size_t)(b * SEQ) * QKW + EMB + h * HDIM;
  const size_t vbase = (size_t)bh * HDIM * SEQ;

  auto stage = [&](int n0, int buf) {   // 4 gld16 per thread
#pragma unroll
    for (int i = 0; i < 2; ++i) {
      const int idx = i * 256 + t, r = idx >> 3;
      const int gc = (((idx & 7) ^ (r & 7)) << 3);
      gld16(qk + kbase + (size_t)(n0 + r) * QKW + gc, &Ks[buf][(size_t)idx * 8]);
      gld16(vT + vbase + (size_t)r * SEQ + n0 + gc,   &Vs[buf][(size_t)idx * 8]);
    }
  };

  // Q frags direct from global: Y-layout [query=l16][k=quad*8+j]
  short8 bq[2][2];
  const u16* qrow = qk + (size_t)(b * SEQ + m0 + w * 32 + l16) * QKW + h * HDIM;
#pragma unroll
  for (int mt = 0; mt < 2; ++mt)
#pragma unroll
    for (int kc = 0; kc < 2; ++kc)
      bq[mt][kc] = *(const short8*)(qrow + (size_t)mt * 16 * QKW + kc * 32 + quad * 8);

  stage(0, 0);
  stage(64, 1);

  short8 ones;
#pragma unroll
  for (int j = 0; j < 8; ++j) ones[j] = (short)0x3F80;  // bf16 1.0
  const floatx4 zf = (floatx4){0.f, 0.f, 0.f, 0.f};

  floatx4 o[2][4], lcc[2];
#pragma unroll
  for (int mt = 0; mt < 2; ++mt) {
    lcc[mt] = zf;
#pragma unroll
    for (int dt = 0; dt < 4; ++dt) o[mt][dt] = zf;
  }

  int cur = 0;
  for (int it = 0; it < ITERS; ++it) {
    int nxt = cur + 2; if (nxt >= 3) nxt -= 3;
    if (it + 2 < ITERS) {
      stage((it + 2) * 64, nxt);
      PIPE_BARRIER_VM(8);      // drain tile it; it+1, it+2 stay in flight
    } else if (it + 1 < ITERS) {
      PIPE_BARRIER_VM(4);
    } else {
      PIPE_BARRIER_VM(0);
    }

    // S^T: st[kt][mt] = D[key=kt*16+quad*4+r][query=l16]  (Q pre-scaled by 1/8*log2e)
    floatx4 st[4][2];
#pragma unroll
    for (int kt = 0; kt < 4; ++kt) {
      const int krow = (kt * 16 + l16) * 64;
      const short8 ak0 = *(const short8*)(&Ks[cur][krow + ((0 ^ (quad ^ swz)) << 3) + ((quad ^ swz) == (quad ^ swz) ? 0 : 0)]);
      const short8 ak1 = *(const short8*)(&Ks[cur][krow + (((4 + quad) ^ swz) << 3)]);
      const short8 ak0f = *(const short8*)(&Ks[cur][krow + ((quad ^ swz) << 3)]);
#pragma unroll
      for (int mt = 0; mt < 2; ++mt) {
        st[kt][mt] = __builtin_amdgcn_mfma_f32_16x16x32_bf16(ak0f, bq[mt][0], zf, 0, 0, 0);
        st[kt][mt] = __builtin_amdgcn_mfma_f32_16x16x32_bf16(ak1, bq[mt][1], st[kt][mt], 0, 0, 0);
      }
      (void)ak0;
    }

    // exp2 in registers -> P^T packed as Y-operand frags (no LDS)
    union { uint4 u; short8 s; } bp[2][2];   // [ktp][mt]
#pragma unroll
    for (int mt = 0; mt < 2; ++mt)
#pragma unroll
      for (int ktp = 0; ktp < 2; ++ktp) {
        const floatx4 e0 = st[2 * ktp][mt], e1 = st[2 * ktp + 1][mt];
        bp[ktp][mt].u.x = pack2bf_t(__builtin_amdgcn_exp2f(e0[0]), __builtin_amdgcn_exp2f(e0[1]));
        bp[ktp][mt].u.y = pack2bf_t(__builtin_amdgcn_exp2f(e0[2]), __builtin_amdgcn_exp2f(e0[3]));
        bp[ktp][mt].u.z = pack2bf_t(__builtin_amdgcn_exp2f(e1[0]), __builtin_amdgcn_exp2f(e1[1]));
        bp[ktp][mt].u.w = pack2bf_t(__builtin_amdgcn_exp2f(e1[2]), __builtin_amdgcn_exp2f(e1[3]));
      }

    // O^T += V*P^T ; l += ones*P^T.  X = V with key-perm pi: two b64 per (dt,ktp).
#pragma unroll
    for (int ktp = 0; ktp < 2; ++ktp) {
      const int gl = 4 * ktp + (quad >> 1), ho = (quad & 1) * 4;
#pragma unroll
      for (int dt = 0; dt < 4; ++dt) {
        const int row = dt * 16 + l16;
        const u16* vr = &Vs[cur][row * 64];
        union { uint4 u; short8 s; } av;
        const uint2 lo = *(const uint2*)(vr + ((gl ^ swz) << 3) + ho);
        const uint2 hi = *(const uint2*)(vr + (((gl + 2) ^ swz) << 3) + ho);
        av.u.x = lo.x; av.u.y = lo.y; av.u.z = hi.x; av.u.w = hi.y;
#pragma unroll
        for (int mt = 0; mt < 2; ++mt)
          o[mt][dt] = __builtin_amdgcn_mfma_f32_16x16x32_bf16(av.s, bp[ktp][mt].s, o[mt][dt], 0, 0, 0);
      }
#pragma unroll
      for (int mt = 0; mt < 2; ++mt)
        lcc[mt] = __builtin_amdgcn_mfma_f32_16x16x32_bf16(ones, bp[ktp][mt].s, lcc[mt], 0, 0, 0);
    }
    PIPE_BARRIER;
    cur = (cur + 1 == 3) ? 0 : cur + 1;
  }

  // epilogue: O^T D[m=d=quad*4+r][n=query=l16]; l indexed by l16 -> in-lane normalize
#pragma unroll
  for (int mt = 0; mt < 2; ++mt) {
    const float inv = 1.f / lcc[mt][0];
    const size_t arow = (size_t)(b * SEQ + m0 + w * 32 + mt * 16 + l16) * EMB + h * HDIM;
#pragma unroll
    for (int dt = 0; dt < 4; ++dt) {
      ushort4 pk;
      pk.x = f2bf(o[mt][dt][0] * inv); pk.y = f2bf(o[mt][dt][1] * inv);
      pk.z = f2bf(o[mt][dt][2] * inv); pk.w = f2bf(o[mt][dt][3] * inv);
      *(ushort4*)(aout + arow + dt * 16 + quad * 4) = pk;
    }
  }
}

// ---------------- out GEMM: [8192,768] x [768,768]^T + bias -> fp32 ----------------
__global__ __launch_bounds__(256) void gemm_out(const u16* __restrict__ A,
                                                const u16* __restrict__ Bt,
                                                const float* __restrict__ bias,
                                                float* __restrict__ C) {
  constexpr int K = EMB, N = EMB, ITERS = K / 64;
  __shared__ __align__(16) u16 As[2][64 * 64];
  __shared__ __align__(16) u16 Bs[2][128 * 64];
  const int t = threadIdx.x;
  const int w = t >> 6, lane = t & 63, l16 = lane & 15, quad = lane >> 4;
  const int wm = (w >> 1) * 32, wn = (w & 1) * 64;
  const int flat = blockIdx.y * 6 + blockIdx.x;
  const int grp = flat / 48, loc = flat % 48;
  const int m0 = (grp * 8 + (loc & 7)) * 64;
  const int n0 = (loc >> 3) * 128;

  auto stage = [&](int k0, int buf) {   // 6 gld16 per thread
#pragma unroll
    for (int i = 0; i < 2; ++i) {
      const int idx = i * 256 + t;
      const int row = idx >> 3;
      const int gc8 = (((idx & 7) ^ (row & 7)) << 3);
      gld16(A + (size_t)(m0 + row) * K + k0 + gc8, &As[buf][(size_t)idx * 8]);
    }
#pragma unroll
    for (int i = 0; i < 4; ++i) {
      const int idx = i * 256 + t;
      const int row = idx >> 3;
      const int gc8 = (((idx & 7) ^ (row & 7)) << 3);
      gld16(Bt + (size_t)(n0 + row) * K + k0 + gc8, &Bs[buf][(size_t)idx * 8]);
    }
  };

  floatx4 acc[2][4];
#pragma unroll
  for (int mt = 0; mt < 2; ++mt)
#pragma unroll
    for (int nt = 0; nt < 4; ++nt) acc[mt][nt] = (floatx4){0.f, 0.f, 0.f, 0.f};

  stage(0, 0);
  for (int it = 0; it < ITERS; ++it) {
    const int cur = it & 1;
    if (it + 1 < ITERS) {
      stage((it + 1) * 64, cur ^ 1);
      PIPE_BARRIER_VM(6);
    } else {
      PIPE_BARRIER_VM(0);
    }
#pragma unroll
    for (int kk = 0; kk < 2; ++kk) {
      short8 a[2], b[4];
#pragma unroll
      for (int mt = 0; mt < 2; ++mt) {
        const int row = wm + mt * 16 + l16;
        a[mt] = *(const short8*)(&As[cur][row * 64 + ((((kk << 2) + quad) ^ (row & 7)) << 3)]);
      }
#pragma unroll
      for (int nt = 0; nt < 4; ++nt) {
        const int row = wn + nt * 16 + l16;
        b[nt] = *(const short8*)(&Bs[cur][row * 64 + ((((kk << 2) + quad) ^ (row & 7)) << 3)]);
      }
#pragma unroll
      for (int mt = 0; mt < 2; ++mt)
#pragma unroll
        for (int nt = 0; nt < 4; ++nt)
          acc[mt][nt] = __builtin_amdgcn_mfma_f32_16x16x32_bf16(a[mt], b[nt], acc[mt][nt], 0, 0, 0);
    }
    PIPE_BARRIER;
  }

#pragma unroll
  for (int mt = 0; mt < 2; ++mt)
#pragma unroll
    for (int nt = 0; nt < 4; ++nt) {
      const int col = n0 + wn + nt * 16 + l16;
      const float badd = bias[col];
#pragma unroll
      for (int r = 0; r < 4; ++r) {
        const int row = m0 + wm + mt * 16 + quad * 4 + r;
        C[(size_t)row * N + col] = acc[mt][nt][r] + badd;
      }
    }
}

// ---------------- launch ----------------
extern "C" void kernel_launch(void* const* d_in, const int* in_sizes, int n_in,
                              void* d_out, int out_size, void* d_ws, size_t ws_size,
                              hipStream_t stream) {
  const float* x     = (const float*)d_in[0];  // [8192, 768]
  const float* w_qkv = (const float*)d_in[1];  // [768, 2304]
  const float* w_out = (const float*)d_in[2];  // [768, 768]
  const float* b_out = (const float*)d_in[3];  // [768]
  float* out = (float*)d_out;                  // [8192, 768] fp32

  // ws (u16 units); xb dead after QKV GEMM -> aliased with aout.
  u16* qk    = (u16*)d_ws;                      // 8192*1536
  u16* vT    = qk    + (size_t)ROWS * QKW;      // 96*64*1024
  u16* xb    = vT    + (size_t)BATCH * NHEADS * HDIM * SEQ;  // 8192*768
  u16* aout  = xb;
  u16* wqkvT = xb    + (size_t)ROWS * EMB;      // 2304*768
  u16* woutT = wqkvT + (size_t)QKVD * EMB;      // 768*768

  prep<<<3072 + 2304, 256, 0, stream>>>(x, w_qkv, w_out, xb, wqkvT, woutT);

  gemm_qkv<<<dim3(18, 64), 256, 0, stream>>>(xb, wqkvT, qk, vT);

  flash_attn<<<dim3(BATCH * NHEADS, SEQ / 128), 256, 0, stream>>>(qk, vT, aout);

  gemm_out<<<dim3(6, 128), 256, 0, stream>>>(aout, woutT, b_out, out);
}

// Round 10
// 170.488 us; speedup vs baseline: 1.0983x; 1.0774x over previous
//
#include <hip/hip_runtime.h>
#include <hip/hip_bf16.h>

typedef unsigned short u16;
typedef __attribute__((ext_vector_type(8))) short short8;   // 8 bf16 = 4 VGPRs (MFMA A/B frag)
typedef __attribute__((ext_vector_type(4))) float floatx4;  // MFMA C/D frag

#define SEQ    1024
#define EMB    768
#define NHEADS 12
#define HDIM   64
#define QKVD   2304   // 3*EMB
#define BATCH  8
#define ROWS   8192   // BATCH*SEQ
#define QKW    1536   // width of the Q|K buffer (V split out)

__device__ __forceinline__ u16 f2bf(float f) {           // RNE
  unsigned int x; __builtin_memcpy(&x, &f, 4);
  x = (x + 0x7FFFu + ((x >> 16) & 1u)) >> 16;
  return (u16)x;
}
// pack two floats' bf16-truncations into one u32 (low = a, high = b)
__device__ __forceinline__ unsigned int pack2bf_t(float a, float b) {
  unsigned int ua, ub;
  __builtin_memcpy(&ua, &a, 4); __builtin_memcpy(&ub, &b, 4);
  return (ub & 0xFFFF0000u) | (ua >> 16);
}

// async global->LDS, 16B per lane. LDS dest must be wave-chunk base + lane*16 (m104);
// the GLOBAL address is per-lane-free, which lets us XOR-permute the source.
__device__ __forceinline__ void gld16(const void* g, void* l) {
  __builtin_amdgcn_global_load_lds(
      (const __attribute__((address_space(1))) void*)g,
      (__attribute__((address_space(3))) void*)l, 16, 0, 0);
}

// raw barrier control: wait only the OLDER tiles' loads (never vmcnt(0) mid-pipeline).
#define PIPE_BARRIER_VM(N) asm volatile("s_waitcnt vmcnt(" #N ")\n\ts_barrier" ::: "memory")
#define PIPE_BARRIER       asm volatile("s_barrier" ::: "memory")

// ---------------- prep: x fp32->bf16 + both weight transposes, one launch ----------------
__global__ __launch_bounds__(256) void prep(const float* __restrict__ x,
                                            const float* __restrict__ wqkv,
                                            const float* __restrict__ wout,
                                            u16* __restrict__ xb,
                                            u16* __restrict__ dqkv,
                                            u16* __restrict__ dout) {
  const int t = threadIdx.x;
  if (blockIdx.x < 3072) {
    const int i = (blockIdx.x * 256 + t) * 8;
    u16 tmp[8];
#pragma unroll
    for (int j = 0; j < 8; ++j) tmp[j] = f2bf(x[i + j]);
    *(uint4*)(xb + i) = *(const uint4*)tmp;
    return;
  }
  __shared__ u16 tile[32][33];
  const int bid = blockIdx.x - 3072;          // [0,2304)
  const int bx = bid % 96, by = bid / 96;
  const bool second = bx >= 72;
  const float* in = second ? wout : wqkv;
  u16* out = second ? dout : dqkv;
  const int C = second ? EMB : QKVD;
  const int c0 = (second ? bx - 72 : bx) * 32, r0 = by * 32;
  const int tx = t & 31, ty = t >> 5;
#pragma unroll
  for (int i = 0; i < 4; ++i)
    tile[ty + i * 8][tx] = f2bf(in[(size_t)(r0 + ty + i * 8) * C + c0 + tx]);
  __syncthreads();
#pragma unroll
  for (int i = 0; i < 4; ++i)
    out[(size_t)(c0 + ty + i * 8) * EMB + r0 + tx] = tile[tx][ty + i * 8];
}

// ---------------- QKV GEMM: [8192,768] x [2304,768]^T -> qk + vT ----------------
// Q columns pre-scaled by 0.125*log2(e) so flash's exp2 needs no multiply.
__global__ __launch_bounds__(256) void gemm_qkv(const u16* __restrict__ A,
                                                const u16* __restrict__ Bt,
                                                u16* __restrict__ qk,
                                                u16* __restrict__ vT) {
  constexpr int K = EMB, ITERS = K / 64;
  __shared__ __align__(16) u16 As[2][128 * 64];
  __shared__ __align__(16) u16 Bs[2][128 * 64];
  const int t = threadIdx.x;
  const int w = t >> 6, lane = t & 63, l16 = lane & 15, quad = lane >> 4;
  const int wm = (w >> 1) * 64, wn = (w & 1) * 64;
  const int flat = blockIdx.y * 18 + blockIdx.x;
  const int grp = flat / 144, loc = flat % 144;
  const int m0 = (grp * 8 + (loc & 7)) * 128;
  const int n0 = (loc >> 3) * 128;

  auto stage = [&](int k0, int buf) {   // 8 gld16 per thread
#pragma unroll
    for (int i = 0; i < 4; ++i) {
      const int idx = i * 256 + t;
      const int row = idx >> 3;
      const int gc8 = (((idx & 7) ^ (row & 7)) << 3);
      gld16(A  + (size_t)(m0 + row) * K + k0 + gc8, &As[buf][(size_t)idx * 8]);
      gld16(Bt + (size_t)(n0 + row) * K + k0 + gc8, &Bs[buf][(size_t)idx * 8]);
    }
  };

  floatx4 acc[4][4];
#pragma unroll
  for (int mt = 0; mt < 4; ++mt)
#pragma unroll
    for (int nt = 0; nt < 4; ++nt) acc[mt][nt] = (floatx4){0.f, 0.f, 0.f, 0.f};

  stage(0, 0);
#pragma unroll
  for (int it = 0; it < ITERS; ++it) {
    const int cur = it & 1;
    if (it + 1 < ITERS) {
      stage((it + 1) * 64, cur ^ 1);
      PIPE_BARRIER_VM(8);
    } else {
      PIPE_BARRIER_VM(0);
    }
#pragma unroll
    for (int kk = 0; kk < 2; ++kk) {
      short8 a[4], b[4];
#pragma unroll
      for (int mt = 0; mt < 4; ++mt) {
        const int row = wm + mt * 16 + l16;
        a[mt] = *(const short8*)(&As[cur][row * 64 + ((((kk << 2) + quad) ^ (row & 7)) << 3)]);
      }
#pragma unroll
      for (int nt = 0; nt < 4; ++nt) {
        const int row = wn + nt * 16 + l16;
        b[nt] = *(const short8*)(&Bs[cur][row * 64 + ((((kk << 2) + quad) ^ (row & 7)) << 3)]);
      }
#pragma unroll
      for (int mt = 0; mt < 4; ++mt)
#pragma unroll
        for (int nt = 0; nt < 4; ++nt)
          acc[mt][nt] = __builtin_amdgcn_mfma_f32_16x16x32_bf16(a[mt], b[nt], acc[mt][nt], 0, 0, 0);
    }
    PIPE_BARRIER;
  }

  if (n0 < QKW) {
    const float qs = (n0 < EMB) ? 0.1803368801111f : 1.0f;  // 0.125*log2(e) on Q cols
#pragma unroll
    for (int mt = 0; mt < 4; ++mt)
#pragma unroll
      for (int nt = 0; nt < 4; ++nt) {
        const int col = n0 + wn + nt * 16 + l16;
#pragma unroll
        for (int r = 0; r < 4; ++r) {
          const int row = m0 + wm + mt * 16 + quad * 4 + r;
          qk[(size_t)row * QKW + col] = f2bf(acc[mt][nt][r] * qs);
        }
      }
  } else {
#pragma unroll
    for (int mt = 0; mt < 4; ++mt) {
      const int rowb = m0 + wm + mt * 16 + quad * 4;
      const int b = rowb >> 10, n = rowb & 1023;
#pragma unroll
      for (int nt = 0; nt < 4; ++nt) {
        const int vc = n0 + wn + nt * 16 + l16 - QKW;
        const int h = vc >> 6, d = vc & 63;
        ushort4 pk;
        pk.x = f2bf(acc[mt][nt][0]); pk.y = f2bf(acc[mt][nt][1]);
        pk.z = f2bf(acc[mt][nt][2]); pk.w = f2bf(acc[mt][nt][3]);
        *(ushort4*)(vT + ((size_t)(b * NHEADS + h) * HDIM + d) * SEQ + n) = pk;
      }
    }
  }
}

// ---------------- flash attention (register-resident P, 2-buffer, full unroll) ------
// grid (B*H, SEQ/128); 4 waves x 32 queries. S^T = mfma(K,Q) -> exp2 in regs ->
// P^T feeds PV MFMA directly as Y-operand (no P LDS). V X-operand via key-perm pi
// (2x ds_read_b64, 2-way banks). l = mfma(ones, P^T), in-lane with O^T.
// LDS = 32 KB (2 K/V buffers) -> 5 blocks/CU; loop fully unrolled -> static LDS addrs.
__global__ __launch_bounds__(256) void flash_attn(const u16* __restrict__ qk,
                                                  const u16* __restrict__ vT,
                                                  u16* __restrict__ aout) {
  __shared__ __align__(16) u16 Ks[2][64 * 64];   // [key][d]
  __shared__ __align__(16) u16 Vs[2][64 * 64];   // [d][key]

  const int t = threadIdx.x;
  const int w = t >> 6, lane = t & 63, l16 = lane & 15, quad = lane >> 4;
  const int bh = blockIdx.x, b = bh / NHEADS, h = bh % NHEADS;
  const int m0 = blockIdx.y * 128;
  constexpr int ITERS = SEQ / 64;
  const int swz = l16 & 7;

  const size_t kbase = (size_t)(b * SEQ) * QKW + EMB + h * HDIM;
  const size_t vbase = (size_t)bh * HDIM * SEQ;

  auto stage = [&](int n0, int buf) {   // 4 gld16 per thread
#pragma unroll
    for (int i = 0; i < 2; ++i) {
      const int idx = i * 256 + t, r = idx >> 3;
      const int gc = (((idx & 7) ^ (r & 7)) << 3);
      gld16(qk + kbase + (size_t)(n0 + r) * QKW + gc, &Ks[buf][(size_t)idx * 8]);
      gld16(vT + vbase + (size_t)r * SEQ + n0 + gc,   &Vs[buf][(size_t)idx * 8]);
    }
  };

  // Q frags direct from global: Y-layout [query=l16][k=quad*8+j] (pre-scaled)
  short8 bq[2][2];
  const u16* qrow = qk + (size_t)(b * SEQ + m0 + w * 32 + l16) * QKW + h * HDIM;
#pragma unroll
  for (int mt = 0; mt < 2; ++mt)
#pragma unroll
    for (int kc = 0; kc < 2; ++kc)
      bq[mt][kc] = *(const short8*)(qrow + (size_t)mt * 16 * QKW + kc * 32 + quad * 8);

  stage(0, 0);

  short8 ones;
#pragma unroll
  for (int j = 0; j < 8; ++j) ones[j] = (short)0x3F80;  // bf16 1.0
  const floatx4 zf = (floatx4){0.f, 0.f, 0.f, 0.f};

  floatx4 o[2][4], lcc[2];
#pragma unroll
  for (int mt = 0; mt < 2; ++mt) {
    lcc[mt] = zf;
#pragma unroll
    for (int dt = 0; dt < 4; ++dt) o[mt][dt] = zf;
  }

#pragma unroll
  for (int it = 0; it < ITERS; ++it) {
    const int cur = it & 1;
    if (it + 1 < ITERS) {
      stage((it + 1) * 64, cur ^ 1);
      PIPE_BARRIER_VM(4);      // drain tile it (+ Q regs on iter 0); it+1 stays in flight
    } else {
      PIPE_BARRIER_VM(0);
    }

    // S^T: st[kt][mt] = D[key=kt*16+quad*4+r][query=l16]
    floatx4 st[4][2];
#pragma unroll
    for (int kt = 0; kt < 4; ++kt) {
      const int krow = (kt * 16 + l16) * 64;
      const short8 ak0 = *(const short8*)(&Ks[cur][krow + ((quad ^ swz) << 3)]);
      const short8 ak1 = *(const short8*)(&Ks[cur][krow + (((4 + quad) ^ swz) << 3)]);
#pragma unroll
      for (int mt = 0; mt < 2; ++mt) {
        st[kt][mt] = __builtin_amdgcn_mfma_f32_16x16x32_bf16(ak0, bq[mt][0], zf, 0, 0, 0);
        st[kt][mt] = __builtin_amdgcn_mfma_f32_16x16x32_bf16(ak1, bq[mt][1], st[kt][mt], 0, 0, 0);
      }
    }

    // exp2 in registers -> P^T packed as Y-operand frags (no LDS)
    union { uint4 u; short8 s; } bp[2][2];   // [ktp][mt]
#pragma unroll
    for (int mt = 0; mt < 2; ++mt)
#pragma unroll
      for (int ktp = 0; ktp < 2; ++ktp) {
        const floatx4 e0 = st[2 * ktp][mt], e1 = st[2 * ktp + 1][mt];
        bp[ktp][mt].u.x = pack2bf_t(__builtin_amdgcn_exp2f(e0[0]), __builtin_amdgcn_exp2f(e0[1]));
        bp[ktp][mt].u.y = pack2bf_t(__builtin_amdgcn_exp2f(e0[2]), __builtin_amdgcn_exp2f(e0[3]));
        bp[ktp][mt].u.z = pack2bf_t(__builtin_amdgcn_exp2f(e1[0]), __builtin_amdgcn_exp2f(e1[1]));
        bp[ktp][mt].u.w = pack2bf_t(__builtin_amdgcn_exp2f(e1[2]), __builtin_amdgcn_exp2f(e1[3]));
      }

    // O^T += V*P^T ; l += ones*P^T.  X = V with key-perm pi: two b64 per (dt,ktp).
#pragma unroll
    for (int ktp = 0; ktp < 2; ++ktp) {
      const int gl = 4 * ktp + (quad >> 1), ho = (quad & 1) * 4;
#pragma unroll
      for (int dt = 0; dt < 4; ++dt) {
        const int row = dt * 16 + l16;
        const u16* vr = &Vs[cur][row * 64];
        union { uint4 u; short8 s; } av;
        const uint2 lo = *(const uint2*)(vr + ((gl ^ swz) << 3) + ho);
        const uint2 hi = *(const uint2*)(vr + (((gl + 2) ^ swz) << 3) + ho);
        av.u.x = lo.x; av.u.y = lo.y; av.u.z = hi.x; av.u.w = hi.y;
#pragma unroll
        for (int mt = 0; mt < 2; ++mt)
          o[mt][dt] = __builtin_amdgcn_mfma_f32_16x16x32_bf16(av.s, bp[ktp][mt].s, o[mt][dt], 0, 0, 0);
      }
#pragma unroll
      for (int mt = 0; mt < 2; ++mt)
        lcc[mt] = __builtin_amdgcn_mfma_f32_16x16x32_bf16(ones, bp[ktp][mt].s, lcc[mt], 0, 0, 0);
    }
    PIPE_BARRIER;
  }

  // epilogue: O^T D[m=d=quad*4+r][n=query=l16]; l indexed by l16 -> in-lane normalize
#pragma unroll
  for (int mt = 0; mt < 2; ++mt) {
    const float inv = 1.f / lcc[mt][0];
    const size_t arow = (size_t)(b * SEQ + m0 + w * 32 + mt * 16 + l16) * EMB + h * HDIM;
#pragma unroll
    for (int dt = 0; dt < 4; ++dt) {
      ushort4 pk;
      pk.x = f2bf(o[mt][dt][0] * inv); pk.y = f2bf(o[mt][dt][1] * inv);
      pk.z = f2bf(o[mt][dt][2] * inv); pk.w = f2bf(o[mt][dt][3] * inv);
      *(ushort4*)(aout + arow + dt * 16 + quad * 4) = pk;
    }
  }
}

// ---------------- out GEMM: [8192,768] x [768,768]^T + bias -> fp32 ----------------
__global__ __launch_bounds__(256) void gemm_out(const u16* __restrict__ A,
                                                const u16* __restrict__ Bt,
                                                const float* __restrict__ bias,
                                                float* __restrict__ C) {
  constexpr int K = EMB, N = EMB, ITERS = K / 64;
  __shared__ __align__(16) u16 As[2][64 * 64];
  __shared__ __align__(16) u16 Bs[2][128 * 64];
  const int t = threadIdx.x;
  const int w = t >> 6, lane = t & 63, l16 = lane & 15, quad = lane >> 4;
  const int wm = (w >> 1) * 32, wn = (w & 1) * 64;
  const int flat = blockIdx.y * 6 + blockIdx.x;
  const int grp = flat / 48, loc = flat % 48;
  const int m0 = (grp * 8 + (loc & 7)) * 64;
  const int n0 = (loc >> 3) * 128;

  auto stage = [&](int k0, int buf) {   // 6 gld16 per thread
#pragma unroll
    for (int i = 0; i < 2; ++i) {
      const int idx = i * 256 + t;
      const int row = idx >> 3;
      const int gc8 = (((idx & 7) ^ (row & 7)) << 3);
      gld16(A + (size_t)(m0 + row) * K + k0 + gc8, &As[buf][(size_t)idx * 8]);
    }
#pragma unroll
    for (int i = 0; i < 4; ++i) {
      const int idx = i * 256 + t;
      const int row = idx >> 3;
      const int gc8 = (((idx & 7) ^ (row & 7)) << 3);
      gld16(Bt + (size_t)(n0 + row) * K + k0 + gc8, &Bs[buf][(size_t)idx * 8]);
    }
  };

  floatx4 acc[2][4];
#pragma unroll
  for (int mt = 0; mt < 2; ++mt)
#pragma unroll
    for (int nt = 0; nt < 4; ++nt) acc[mt][nt] = (floatx4){0.f, 0.f, 0.f, 0.f};

  stage(0, 0);
#pragma unroll
  for (int it = 0; it < ITERS; ++it) {
    const int cur = it & 1;
    if (it + 1 < ITERS) {
      stage((it + 1) * 64, cur ^ 1);
      PIPE_BARRIER_VM(6);
    } else {
      PIPE_BARRIER_VM(0);
    }
#pragma unroll
    for (int kk = 0; kk < 2; ++kk) {
      short8 a[2], b[4];
#pragma unroll
      for (int mt = 0; mt < 2; ++mt) {
        const int row = wm + mt * 16 + l16;
        a[mt] = *(const short8*)(&As[cur][row * 64 + ((((kk << 2) + quad) ^ (row & 7)) << 3)]);
      }
#pragma unroll
      for (int nt = 0; nt < 4; ++nt) {
        const int row = wn + nt * 16 + l16;
        b[nt] = *(const short8*)(&Bs[cur][row * 64 + ((((kk << 2) + quad) ^ (row & 7)) << 3)]);
      }
#pragma unroll
      for (int mt = 0; mt < 2; ++mt)
#pragma unroll
        for (int nt = 0; nt < 4; ++nt)
          acc[mt][nt] = __builtin_amdgcn_mfma_f32_16x16x32_bf16(a[mt], b[nt], acc[mt][nt], 0, 0, 0);
    }
    PIPE_BARRIER;
  }

#pragma unroll
  for (int mt = 0; mt < 2; ++mt)
#pragma unroll
    for (int nt = 0; nt < 4; ++nt) {
      const int col = n0 + wn + nt * 16 + l16;
      const float badd = bias[col];
#pragma unroll
      for (int r = 0; r < 4; ++r) {
        const int row = m0 + wm + mt * 16 + quad * 4 + r;
        C[(size_t)row * N + col] = acc[mt][nt][r] + badd;
      }
    }
}

// ---------------- launch ----------------
extern "C" void kernel_launch(void* const* d_in, const int* in_sizes, int n_in,
                              void* d_out, int out_size, void* d_ws, size_t ws_size,
                              hipStream_t stream) {
  const float* x     = (const float*)d_in[0];  // [8192, 768]
  const float* w_qkv = (const float*)d_in[1];  // [768, 2304]
  const float* w_out = (const float*)d_in[2];  // [768, 768]
  const float* b_out = (const float*)d_in[3];  // [768]
  float* out = (float*)d_out;                  // [8192, 768] fp32

  // ws (u16 units); xb dead after QKV GEMM -> aliased with aout.
  u16* qk    = (u16*)d_ws;                      // 8192*1536
  u16* vT    = qk    + (size_t)ROWS * QKW;      // 96*64*1024
  u16* xb    = vT    + (size_t)BATCH * NHEADS * HDIM * SEQ;  // 8192*768
  u16* aout  = xb;
  u16* wqkvT = xb    + (size_t)ROWS * EMB;      // 2304*768
  u16* woutT = wqkvT + (size_t)QKVD * EMB;      // 768*768

  prep<<<3072 + 2304, 256, 0, stream>>>(x, w_qkv, w_out, xb, wqkvT, woutT);

  gemm_qkv<<<dim3(18, 64), 256, 0, stream>>>(xb, wqkvT, qk, vT);

  flash_attn<<<dim3(BATCH * NHEADS, SEQ / 128), 256, 0, stream>>>(qk, vT, aout);

  gemm_out<<<dim3(6, 128), 256, 0, stream>>>(aout, woutT, b_out, out);
}